// Round 3
// baseline (156.486 us; speedup 1.0000x reference)
//
#include <hip/hip_runtime.h>
#include <hip/hip_bf16.h>
#include <stdint.h>

// Correlation (FlowNet), md=4: out[b, di*9+dj, h, w] = sum_c x[b,c,h,w]*yp[b,c,h+di-4,w+dj-4] / 256
// R2: 128B-aligned tr subtiles, CHUNK=16 double-buffered LDS (load t+1 before compute t,
// convert after compute), 16 waves/CU target (acc 72 regs -> 4 waves/SIMD cap).

using f32x4 = __attribute__((ext_vector_type(4))) float;
using s16x4 = __attribute__((ext_vector_type(4))) short;
using u16x4 = __attribute__((ext_vector_type(4))) unsigned short;

#define C_DIM 256
#define H_DIM 96
#define W_DIM 192
#define HWSZ  (H_DIM * W_DIM)
#define MD 4
#define KD 9
#define CHUNK 16
#define NCHUNK (C_DIM / CHUNK)   // 16
#define HR 8
#define NTHR 512
#define WTILES 12                // 192/16
#define HQ 12                    // 96/8
#define SUB_B 128                // [4c][16s] bf16 subtile, 128B-aligned (tr unit native)
#define YROW_B (8 * SUB_B)       // 2 t * 4 cg = 1024B per y row (16ch chunk)
#define XROW_B (4 * SUB_B)       // 512B per x row
#define YSZ    (16 * YROW_B)     // 16384
#define XBASE  YSZ
#define BUFSZ  (YSZ + 8 * XROW_B)   // 20480
#define LDS_BYTES (2 * BUFSZ)       // 40960

static __device__ __forceinline__ unsigned short bf16b(float f) {
  __bf16 h = (__bf16)f;                   // RNE
  unsigned short s; __builtin_memcpy(&s, &h, 2); return s;
}

// per-lane: reads column (l&15) of the 128B [4c][16s] bf16 subtile containing addr
static __device__ __forceinline__ s16x4 tr16(uint32_t addr) {
  s16x4 d;
  asm volatile("ds_read_b64_tr_b16 %0, %1" : "=v"(d) : "v"(addr));
  return d;
}

__global__ __launch_bounds__(NTHR, 4)
void corr_mfma(const float* __restrict__ xg, const float* __restrict__ yg,
               float* __restrict__ outg) {
  __shared__ __align__(16) char smem[LDS_BYTES];

  const int bid = blockIdx.x;             // 1152 = 8 * 144
  const int b   = bid & 7;                // batch == XCD round-robin
  const int rem = bid >> 3;               // hq fastest -> h-halo L2 reuse
  const int wt  = rem / HQ;
  const int hq  = rem - wt * HQ;
  const int w0  = wt * 16;
  const int h0  = hq * HR;

  const int tid  = threadIdx.x;
  const int lane = tid & 63;
  const int wv   = tid >> 6;              // wave -> output row h0+wv
  const int hi   = lane >> 4;
  const int lm   = lane & 15;

  const uint32_t sbase = (uint32_t)(uintptr_t)&smem[0];

  // ---- staging decode, hoisted. y: 16 rows x 16c x 6 quads = 3/thread; x: 8 x 16c x 4q = 1/thread
  uint32_t goffY[3], loffY[3], goffX, loffX;
  uint32_t vmY = 0;
#pragma unroll
  for (int i = 0; i < 3; ++i) {
    const int qid = i * NTHR + tid;
    const int q = qid % 6;
    const int c = (qid / 6) & 15;
    const int r = qid / 96;               // 0..15 -> y row h0+r-4
    const int hg = h0 + r - MD;
    const int sg = w0 - MD + 4 * q;       // 4-aligned: OOB is whole-quad
    const bool ok = (hg >= 0) && (hg < H_DIM) && (sg >= 0) && (sg < W_DIM);
    if (ok) vmY |= (1u << i);
    goffY[i] = ok ? (uint32_t)(((b * C_DIM + c) * H_DIM + hg) * W_DIM + sg) : 0u;
    const int s = 4 * q;
    loffY[i] = r * YROW_B + (s >> 4) * 512 + (c >> 2) * SUB_B + (c & 3) * 32 + (s & 15) * 2;
  }
  {
    const int q = tid & 3;                // x staged without w-halo
    const int c = (tid >> 2) & 15;
    const int r = tid >> 6;
    goffX = (uint32_t)(((b * C_DIM + c) * H_DIM + (h0 + r)) * W_DIM + (w0 + 4 * q));
    loffX = XBASE + r * XROW_B + (c >> 2) * SUB_B + (c & 3) * 32 + 8 * q;
  }

  f32x4 acc[KD][2];
#pragma unroll
  for (int di = 0; di < KD; ++di) {
    acc[di][0] = f32x4{0.f, 0.f, 0.f, 0.f};
    acc[di][1] = f32x4{0.f, 0.f, 0.f, 0.f};
  }

  const uint32_t abase = sbase + XBASE + wv * XROW_B + hi * SUB_B + lm * 8;
  const uint32_t bbase = sbase + wv * YROW_B + hi * SUB_B + lm * 8;

  float4 v[4];
  u16x4  wreg[4];

  // ---- prologue: stage chunk 0 into buf0
#pragma unroll
  for (int i = 0; i < 3; ++i) {
    float4 t4 = make_float4(0.f, 0.f, 0.f, 0.f);
    if (vmY & (1u << i)) t4 = *(const float4*)(yg + goffY[i]);
    v[i] = t4;
  }
  v[3] = *(const float4*)(xg + goffX);
#pragma unroll
  for (int i = 0; i < 4; ++i)
    wreg[i] = u16x4{bf16b(v[i].x), bf16b(v[i].y), bf16b(v[i].z), bf16b(v[i].w)};
#pragma unroll
  for (int i = 0; i < 3; ++i) *(u16x4*)(smem + loffY[i]) = wreg[i];
  *(u16x4*)(smem + loffX) = wreg[3];
  __syncthreads();

  for (int t = 0; t < NCHUNK; ++t) {
    // ---- issue next chunk's global loads (latency hides under compute below)
    if (t + 1 < NCHUNK) {
      const uint32_t co = (uint32_t)(t + 1) * CHUNK * HWSZ;
#pragma unroll
      for (int i = 0; i < 3; ++i) {
        float4 t4 = make_float4(0.f, 0.f, 0.f, 0.f);
        if (vmY & (1u << i)) t4 = *(const float4*)(yg + goffY[i] + co);
        v[i] = t4;
      }
      v[3] = *(const float4*)(xg + goffX + co);
    }

    // ---- compute chunk t from buf[t&1]
    const uint32_t bo = (uint32_t)(t & 1) * BUFSZ;
    s16x4 afr = tr16(abase + bo);
    s16x4 b0 = tr16(bbase + bo);
    s16x4 b1 = tr16(bbase + bo + 512);
#pragma unroll
    for (int di = 0; di < KD; ++di) {
      s16x4 n0, n1;
      if (di < 8) {
        const uint32_t bb = bbase + bo + (uint32_t)(di + 1) * YROW_B;
        n0 = tr16(bb);
        n1 = tr16(bb + 512);
        asm volatile("s_waitcnt lgkmcnt(2)" ::: "memory");
      } else {
        asm volatile("s_waitcnt lgkmcnt(0)" ::: "memory");
      }
      __builtin_amdgcn_sched_barrier(0);  // rule #18
      acc[di][0] = __builtin_amdgcn_mfma_f32_16x16x16bf16_1k(afr, b0, acc[di][0], 0, 0, 0);
      acc[di][1] = __builtin_amdgcn_mfma_f32_16x16x16bf16_1k(afr, b1, acc[di][1], 0, 0, 0);
      if (di < 8) { b0 = n0; b1 = n1; }
    }

    // ---- convert (vmcnt wait lands here, after compute) + store to buf[(t+1)&1]
    if (t + 1 < NCHUNK) {
#pragma unroll
      for (int i = 0; i < 4; ++i)
        wreg[i] = u16x4{bf16b(v[i].x), bf16b(v[i].y), bf16b(v[i].z), bf16b(v[i].w)};
      __syncthreads();                    // all waves done reading buf[(t+1)&1]
      const uint32_t wo = (uint32_t)((t + 1) & 1) * BUFSZ;
#pragma unroll
      for (int i = 0; i < 3; ++i) *(u16x4*)(smem + wo + loffY[i]) = wreg[i];
      *(u16x4*)(smem + wo + loffX) = wreg[3];
      __syncthreads();                    // writes visible
    }
  }

  // ---- epilogue: D[m][n]: n=lm, m=hi*4+rg. dj = t*16 + lm - m.
  const int h = h0 + wv;
  const float scale = 1.f / 256.f;
#pragma unroll
  for (int di = 0; di < KD; ++di) {
#pragma unroll
    for (int t = 0; t < 2; ++t) {
#pragma unroll
      for (int rg = 0; rg < 4; ++rg) {
        const int m = hi * 4 + rg;
        const int dj = t * 16 + lm - m;
        if (0 <= dj && dj <= 8) {
          outg[((b * (KD * KD) + di * KD + dj) * H_DIM + h) * W_DIM + w0 + m] =
              acc[di][t][rg] * scale;
        }
      }
    }
  }
}

extern "C" void kernel_launch(void* const* d_in, const int* in_sizes, int n_in,
                              void* d_out, int out_size, void* d_ws, size_t ws_size,
                              hipStream_t stream) {
  const float* x = (const float*)d_in[0];
  const float* y = (const float*)d_in[1];
  float* out = (float*)d_out;
  (void)in_sizes; (void)n_in; (void)d_ws; (void)ws_size; (void)out_size;

  const int grid = 8 * HQ * WTILES;       // 1152 blocks, 512 threads
  corr_mfma<<<dim3(grid), dim3(NTHR), 0, stream>>>(x, y, out);
}

// Round 4
// 156.271 us; speedup vs baseline: 1.0014x; 1.0014x over previous
//
#include <hip/hip_runtime.h>
#include <hip/hip_bf16.h>
#include <stdint.h>

// Correlation (FlowNet), md=4: out[b, di*9+dj, h, w] = sum_c x[b,c,h,w]*yp[b,c,h+di-4,w+dj-4] / 256
// R3: regs<=128 (4 waves/SIMD -> 2 blocks/CU), 3-deep pipelined tr reads with
// counted lgkmcnt, single barrier per chunk, setprio around compute.

using f32x4 = __attribute__((ext_vector_type(4))) float;
using s16x4 = __attribute__((ext_vector_type(4))) short;
using u16x4 = __attribute__((ext_vector_type(4))) unsigned short;

#define C_DIM 256
#define H_DIM 96
#define W_DIM 192
#define HWSZ  (H_DIM * W_DIM)
#define MD 4
#define KD 9
#define CHUNK 16
#define NCHUNK 16
#define HR 8
#define NTHR 512
#define WTILES 12                // 192/16
#define HQ 12                    // 96/8
#define SUB_B 128                // [4c][16s] bf16 subtile, 128B-aligned
#define YROW_B (8 * SUB_B)       // 1024 B per y row (2 t-tiles x 4 cg)
#define XROW_B (4 * SUB_B)       // 512 B per x row
#define XBASE  (16 * YROW_B)     // 16384
#define BUFSZ  (XBASE + 8 * XROW_B)  // 20480
#define LDS_BYTES (2 * BUFSZ)        // 40960

static __device__ __forceinline__ unsigned short bf16b(float f) {
  __bf16 h = (__bf16)f;                   // RNE
  unsigned short s; __builtin_memcpy(&s, &h, 2); return s;
}

static __device__ __forceinline__ s16x4 tr16(uint32_t addr) {
  s16x4 d;
  asm volatile("ds_read_b64_tr_b16 %0, %1" : "=v"(d) : "v"(addr));
  return d;
}

#define WAITLG(n) asm volatile("s_waitcnt lgkmcnt(" #n ")" ::: "memory")

__global__ __launch_bounds__(NTHR, 4)
void corr_mfma(const float* __restrict__ xg, const float* __restrict__ yg,
               float* __restrict__ outg) {
  __shared__ __align__(16) char smem[LDS_BYTES];

  const int bid = blockIdx.x;             // 1152 = 8 * 144
  const int b   = bid & 7;                // batch == XCD round-robin
  const int rem = bid >> 3;               // hq fastest -> h-halo L2 reuse
  const int wt  = rem / HQ;
  const int hq  = rem - wt * HQ;
  const int w0  = wt * 16;
  const int h0  = hq * HR;

  const int tid  = threadIdx.x;
  const int lane = tid & 63;
  const int wv   = tid >> 6;              // wave -> output row h0+wv
  const int hi   = lane >> 4;
  const int lm   = lane & 15;

  const uint32_t sbase = (uint32_t)(uintptr_t)&smem[0];

  // ---- staging decode, hoisted. y: 16 rows x 16c x 6 quads = 3/thread; x: 1/thread
  uint32_t goffY[3], loffY[3], goffX, loffX;
  uint32_t vmY = 0;
#pragma unroll
  for (int i = 0; i < 3; ++i) {
    const int qid = i * NTHR + tid;
    const int q = qid % 6;
    const int c = (qid / 6) & 15;
    const int r = qid / 96;               // 0..15 -> y row h0+r-4
    const int hg = h0 + r - MD;
    const int sg = w0 - MD + 4 * q;       // 4-aligned: OOB is whole-quad
    const bool ok = (hg >= 0) && (hg < H_DIM) && (sg >= 0) && (sg < W_DIM);
    if (ok) vmY |= (1u << i);
    goffY[i] = ok ? (uint32_t)(((b * C_DIM + c) * H_DIM + hg) * W_DIM + sg) : 0u;
    const int s = 4 * q;
    loffY[i] = r * YROW_B + (s >> 4) * 512 + (c >> 2) * SUB_B + (c & 3) * 32 + (s & 15) * 2;
  }
  {
    const int q = tid & 3;                // x staged without w-halo
    const int c = (tid >> 2) & 15;
    const int r = tid >> 6;
    goffX = (uint32_t)(((b * C_DIM + c) * H_DIM + (h0 + r)) * W_DIM + (w0 + 4 * q));
    loffX = XBASE + r * XROW_B + (c >> 2) * SUB_B + (c & 3) * 32 + 8 * q;
  }

  f32x4 acc[KD][2];
#pragma unroll
  for (int di = 0; di < KD; ++di) {
    acc[di][0] = f32x4{0.f, 0.f, 0.f, 0.f};
    acc[di][1] = f32x4{0.f, 0.f, 0.f, 0.f};
  }

  const uint32_t abase = sbase + XBASE + wv * XROW_B + hi * SUB_B + lm * 8;
  const uint32_t bbase = sbase + wv * YROW_B + hi * SUB_B + lm * 8;

  // ---- prologue: stage chunk 0 into buf0
  {
    float4 v[4];
#pragma unroll
    for (int i = 0; i < 3; ++i) {
      float4 t4 = make_float4(0.f, 0.f, 0.f, 0.f);
      if (vmY & (1u << i)) t4 = *(const float4*)(yg + goffY[i]);
      v[i] = t4;
    }
    v[3] = *(const float4*)(xg + goffX);
#pragma unroll
    for (int i = 0; i < 3; ++i)
      *(u16x4*)(smem + loffY[i]) = u16x4{bf16b(v[i].x), bf16b(v[i].y), bf16b(v[i].z), bf16b(v[i].w)};
    *(u16x4*)(smem + loffX) = u16x4{bf16b(v[3].x), bf16b(v[3].y), bf16b(v[3].z), bf16b(v[3].w)};
  }
  __syncthreads();

  for (int t = 0; t < NCHUNK; ++t) {
    // ---- issue next chunk's global loads (latency hides under this chunk's compute)
    float4 v[4];
    if (t + 1 < NCHUNK) {
      const uint32_t co = (uint32_t)(t + 1) * CHUNK * HWSZ;
#pragma unroll
      for (int i = 0; i < 3; ++i) {
        float4 t4 = make_float4(0.f, 0.f, 0.f, 0.f);
        if (vmY & (1u << i)) t4 = *(const float4*)(yg + goffY[i] + co);
        v[i] = t4;
      }
      v[3] = *(const float4*)(xg + goffX + co);
    }

    // ---- compute chunk t from buf[t&1]: 3-deep pipelined tr reads, counted waits
    const uint32_t bo = (uint32_t)(t & 1) * BUFSZ;
    s16x4 afr;
    s16x4 bf[4][2];

#define ISSUE_PAIR(slot, row) \
    bf[(slot) & 3][0] = tr16(bbase + bo + (uint32_t)(row) * YROW_B); \
    bf[(slot) & 3][1] = tr16(bbase + bo + (uint32_t)(row) * YROW_B + 512);

#define DO_DI(di, lg) \
    WAITLG(lg); __builtin_amdgcn_sched_barrier(0); \
    acc[di][0] = __builtin_amdgcn_mfma_f32_16x16x16bf16_1k(afr, bf[(di) & 3][0], acc[di][0], 0, 0, 0); \
    acc[di][1] = __builtin_amdgcn_mfma_f32_16x16x16bf16_1k(afr, bf[(di) & 3][1], acc[di][1], 0, 0, 0);

    __builtin_amdgcn_s_setprio(1);
    afr = tr16(abase + bo);
    ISSUE_PAIR(0, 0)
    ISSUE_PAIR(1, 1)
    ISSUE_PAIR(2, 2)
    ISSUE_PAIR(3, 3)
    DO_DI(0, 6)
    ISSUE_PAIR(4, 4)
    DO_DI(1, 6)
    ISSUE_PAIR(5, 5)
    DO_DI(2, 6)
    ISSUE_PAIR(6, 6)
    DO_DI(3, 6)
    ISSUE_PAIR(7, 7)
    DO_DI(4, 6)
    ISSUE_PAIR(8, 8)
    DO_DI(5, 6)
    DO_DI(6, 4)
    DO_DI(7, 2)
    DO_DI(8, 0)
    __builtin_amdgcn_s_setprio(0);

#undef ISSUE_PAIR
#undef DO_DI

    // ---- convert (vmcnt wait lands here) + store to buf[(t+1)&1]
    if (t + 1 < NCHUNK) {
      const uint32_t wo = (uint32_t)((t + 1) & 1) * BUFSZ;
#pragma unroll
      for (int i = 0; i < 3; ++i)
        *(u16x4*)(smem + wo + loffY[i]) =
            u16x4{bf16b(v[i].x), bf16b(v[i].y), bf16b(v[i].z), bf16b(v[i].w)};
      *(u16x4*)(smem + wo + loffX) =
          u16x4{bf16b(v[3].x), bf16b(v[3].y), bf16b(v[3].z), bf16b(v[3].w)};
    }
    // single barrier per chunk: after write(t), every wave has passed compute(t),
    // so writing buf[t&1] at chunk t+1 is safe (it was last read in compute(t)).
    __syncthreads();
  }

  // ---- epilogue: D[m][n]: n=lm, m=hi*4+rg. dj = t*16 + lm - m.
  const int h = h0 + wv;
  const float scale = 1.f / 256.f;
#pragma unroll
  for (int di = 0; di < KD; ++di) {
#pragma unroll
    for (int t = 0; t < 2; ++t) {
#pragma unroll
      for (int rg = 0; rg < 4; ++rg) {
        const int m = hi * 4 + rg;
        const int dj = t * 16 + lm - m;
        if (0 <= dj && dj <= 8) {
          outg[((b * (KD * KD) + di * KD + dj) * H_DIM + h) * W_DIM + w0 + m] =
              acc[di][t][rg] * scale;
        }
      }
    }
  }
}

extern "C" void kernel_launch(void* const* d_in, const int* in_sizes, int n_in,
                              void* d_out, int out_size, void* d_ws, size_t ws_size,
                              hipStream_t stream) {
  const float* x = (const float*)d_in[0];
  const float* y = (const float*)d_in[1];
  float* out = (float*)d_out;
  (void)in_sizes; (void)n_in; (void)d_ws; (void)ws_size; (void)out_size;

  const int grid = 8 * HQ * WTILES;       // 1152 blocks, 512 threads
  corr_mfma<<<dim3(grid), dim3(NTHR), 0, stream>>>(x, y, out);
}